// Round 7
// baseline (770.140 us; speedup 1.0000x reference)
//
#include <hip/hip_runtime.h>
#include <math.h>

#define N_TOT 32768
#define NNBR 15
#define APW 8
#define ELP 36
#define ETP 20
#define PLP 20

typedef __attribute__((ext_vector_type(8))) _Float16 f16x8;
typedef __attribute__((ext_vector_type(2))) _Float16 f16x2;
typedef __attribute__((ext_vector_type(4))) float f32x4;

#define CBAR() __asm__ volatile("" ::: "memory")

__device__ __forceinline__ _Float16 f2h(float x) { return (_Float16)x; }

// ---------------------------------------------------------------- frames
__global__ __launch_bounds__(256) void k_frames(const float* __restrict__ tert,
                                                float* __restrict__ pos,
                                                float* __restrict__ R) {
  int n = blockIdx.x * 256 + threadIdx.x;
  if (n >= N_TOT) return;
  float px = tert[n * 9 + 3], py = tert[n * 9 + 4], pz = tert[n * 9 + 5];
  pos[n * 3 + 0] = px; pos[n * 3 + 1] = py; pos[n * 3 + 2] = pz;

  int i0 = (n > 0) ? (n - 1) : 0;
  int i1 = (n < N_TOT - 1) ? n : (N_TOT - 2);

  float ax = tert[(i0 + 1) * 9 + 3] - tert[i0 * 9 + 3];
  float ay = tert[(i0 + 1) * 9 + 4] - tert[i0 * 9 + 4];
  float az = tert[(i0 + 1) * 9 + 5] - tert[i0 * 9 + 5];
  float il = 1.f / (sqrtf(ax * ax + ay * ay + az * az) + 1e-8f);
  float ux = ax * il, uy = ay * il, uz = az * il;

  float cx = tert[(i1 + 1) * 9 + 3] - tert[i1 * 9 + 3];
  float cy = tert[(i1 + 1) * 9 + 4] - tert[i1 * 9 + 4];
  float cz = tert[(i1 + 1) * 9 + 5] - tert[i1 * 9 + 5];
  il = 1.f / (sqrtf(cx * cx + cy * cy + cz * cz) + 1e-8f);
  float vx = cx * il, vy = cy * il, vz = cz * il;

  float bx = ux - vx, by = uy - vy, bz = uz - vz;
  il = 1.f / (sqrtf(bx * bx + by * by + bz * bz) + 1e-8f);
  bx *= il; by *= il; bz *= il;

  float nx = uy * vz - uz * vy;
  float ny = uz * vx - ux * vz;
  float nz = ux * vy - uy * vx;
  il = 1.f / (sqrtf(nx * nx + ny * ny + nz * nz) + 1e-8f);
  nx *= il; ny *= il; nz *= il;

  float ex = by * nz - bz * ny;
  float ey = bz * nx - bx * nz;
  float ez = bx * ny - by * nx;

  float* Rn = R + (size_t)n * 9;
  Rn[0] = bx; Rn[1] = nx; Rn[2] = ex;
  Rn[3] = by; Rn[4] = ny; Rn[5] = ey;
  Rn[6] = bz; Rn[7] = nz; Rn[8] = ez;
}

// ---------------------------------------------------------------- kNN: sorted per-lane lists + u64 butterfly
#define CE(i, j) { unsigned long long _a = key[i], _b = key[j]; \
                   key[i] = _a > _b ? _a : _b; key[j] = _a > _b ? _b : _a; }
__global__ __launch_bounds__(256) void k_knn(const float* __restrict__ pos,
                                             const float* __restrict__ noise,
                                             int* __restrict__ nbr) {
  int wave = threadIdx.x >> 6, lane = threadIdx.x & 63;
  int row = blockIdx.x * 4 + wave;
  int b = row >> 9;
  float pix = pos[row * 3 + 0], piy = pos[row * 3 + 1], piz = pos[row * 3 + 2];
  const float* nrow = noise + (size_t)row * 512;
  const float* pb = pos + (size_t)b * 512 * 3;
  unsigned long long key[8];
#pragma unroll
  for (int jj = 0; jj < 8; jj++) {
    int j = lane + jj * 64;
    float dx = pb[j * 3 + 0] - pix;
    float dy = pb[j * 3 + 1] - piy;
    float dz = pb[j * 3 + 2] - piz;
    float c = -sqrtf(dx * dx + dy * dy + dz * dz) + 3.f * nrow[j];
    unsigned u = __float_as_uint(c);
    unsigned s = u ^ (unsigned)(((int)u >> 31) | (int)0x80000000);
    key[jj] = ((unsigned long long)s << 9) | (unsigned)(511 - j);
  }
  // Batcher odd-even mergesort, descending (19 CE)
  CE(0, 1) CE(2, 3) CE(0, 2) CE(1, 3) CE(1, 2)
  CE(4, 5) CE(6, 7) CE(4, 6) CE(5, 7) CE(5, 6)
  CE(0, 4) CE(1, 5) CE(2, 6) CE(3, 7)
  CE(2, 4) CE(3, 5)
  CE(1, 2) CE(3, 4) CE(5, 6)

  unsigned long long head = key[0];
  int jmine = 0;
#pragma unroll 1
  for (int it = 0; it < NNBR; it++) {
    unsigned long long g = head;
#pragma unroll
    for (int m = 1; m < 64; m <<= 1) {
      unsigned long long og = __shfl_xor(g, m);
      g = og > g ? og : g;
    }
    int j = 511 - (int)(g & 511ull);
    if (lane == it) jmine = j;
    bool won = (head == g);
#pragma unroll
    for (int i = 0; i < 7; i++) key[i] = won ? key[i + 1] : key[i];
    key[7] = won ? 0ull : key[7];
    head = key[0];
  }
  if (lane < NNBR) nbr[(size_t)row * NNBR + lane] = b * 512 + jmine;
}

// ---------------------------------------------------------------- edge features (fp16, 32-padded rows)
__global__ __launch_bounds__(256) void k_edge(const float* __restrict__ pos,
                                              const float* __restrict__ R,
                                              const int* __restrict__ nbr,
                                              _Float16* __restrict__ edge) {
  int idx = blockIdx.x * 256 + threadIdx.x;
  if (idx >= N_TOT * NNBR) return;
  int n = idx / NNBR;
  int m = nbr[idx];
  float dx = pos[m * 3 + 0] - pos[n * 3 + 0];
  float dy = pos[m * 3 + 1] - pos[n * 3 + 1];
  float dz = pos[m * 3 + 2] - pos[n * 3 + 2];
  float d = sqrtf(dx * dx + dy * dy + dz * dz);
  _Float16* e = edge + (size_t)idx * 32;
#pragma unroll
  for (int j = 0; j < 16; j++) {
    float mu = (20.f / 15.f) * (float)j;
    float t = (d - mu) * 0.8f;
    e[j] = f2h(__expf(-t * t));
  }
  float inv = 1.f / (d + 1e-8f);
  float ux = dx * inv, uy = dy * inv, uz = dz * inv;
  float Rn[9], Rm[9];
#pragma unroll
  for (int j = 0; j < 9; j++) { Rn[j] = R[(size_t)n * 9 + j]; Rm[j] = R[(size_t)m * 9 + j]; }
#pragma unroll
  for (int cc = 0; cc < 3; cc++)
    e[16 + cc] = f2h(Rn[0 * 3 + cc] * ux + Rn[1 * 3 + cc] * uy + Rn[2 * 3 + cc] * uz);
#pragma unroll
  for (int cc = 0; cc < 3; cc++)
#pragma unroll
    for (int dd = 0; dd < 3; dd++)
      e[19 + cc * 3 + dd] = f2h(Rn[0 * 3 + cc] * Rm[0 * 3 + dd] +
                                Rn[1 * 3 + cc] * Rm[1 * 3 + dd] +
                                Rn[2 * 3 + cc] * Rm[2 * 3 + dd]);
  e[28] = f2h((float)(m - n));
  e[29] = (_Float16)0.f; e[30] = (_Float16)0.f; e[31] = (_Float16)0.f;
}

// ---------------------------------------------------------------- h init (fp16)
__global__ __launch_bounds__(256) void k_hinit(const float* __restrict__ ew,
                                               const float* __restrict__ ebias,
                                               _Float16* __restrict__ h) {
  __shared__ float hv[128];
  int tid = threadIdx.x;
  if (tid < 128) {
    float s = ebias[tid];
#pragma unroll
    for (int i = 0; i < 27; i++) s += ew[i * 128 + tid];
    hv[tid] = s;
  }
  __syncthreads();
  size_t total = (size_t)N_TOT * 128;
  for (size_t j = (size_t)blockIdx.x * 256 + tid; j < total; j += (size_t)gridDim.x * 256)
    h[j] = f2h(hv[j & 127]);
}

// ---------------------------------------------------------------- dense weight prep: fp32 [k][n] -> fp16 [n][k]
__global__ __launch_bounds__(256) void k_prepw(const float* __restrict__ wq, const float* __restrict__ wk,
                                               const float* __restrict__ wv, const float* __restrict__ wo,
                                               const float* __restrict__ w1, const float* __restrict__ w2,
                                               const float* __restrict__ w3, _Float16* __restrict__ wbt) {
  int idx = blockIdx.x * 256 + threadIdx.x;
  if (idx >= 3 * 7 * 16384) return;
  int l = idx / (7 * 16384);
  int r = idx % (7 * 16384);
  int w = r / 16384;
  int e = r % 16384;
  int k = e >> 7, n = e & 127;
  float val;
  switch (w) {
    case 0: val = wq[(size_t)l * 16384 + e]; break;
    case 1: val = wk[(size_t)l * 157 * 128 + e]; break;
    case 2: val = wv[(size_t)l * 157 * 128 + e]; break;
    case 3: val = wo[(size_t)l * 16384 + e]; break;
    case 4: val = w1[(size_t)l * 16384 + e]; break;
    case 5: val = w2[(size_t)l * 16384 + e]; break;
    default: val = w3[(size_t)l * 16384 + e]; break;
  }
  wbt[(size_t)(l * 7 + w) * 16384 + n * 128 + k] = f2h(val);
}

// ---------------------------------------------------------------- Wqk composite (j = h*32+e layout)
__global__ __launch_bounds__(256) void k_prepqk(const float* __restrict__ wq,
                                                const float* __restrict__ wk,
                                                _Float16* __restrict__ wqk) {
  int idx = blockIdx.x * 256 + threadIdx.x;
  if (idx >= 3 * 2 * 16384) return;
  int l = idx / 32768;
  int r = idx % 32768;
  int blk = r >> 14;
  int jp = (r >> 7) & 127;
  int c = r & 127;
  int j = blk * 128 + jp;        // j = h*32 + e
  int hh = j >> 5, e = j & 31;
  float val = 0.f;
  if (e < 29) {
    const float* wqp = wq + (size_t)l * 16384 + (size_t)c * 128 + hh * 16;
    const float* wkp = wk + (size_t)l * 157 * 128 + (size_t)(128 + e) * 128 + hh * 16;
    float s = 0.f;
#pragma unroll
    for (int d = 0; d < 16; d++) s = fmaf(wqp[d], wkp[d], s);
    val = 0.25f * s;
  }
  wqk[(size_t)idx] = f2h(val);
}

// ---------------------------------------------------------------- wpe = Wv_e'' @ Wo (j = e*8+h layout)
__global__ __launch_bounds__(256) void k_preppe(const float* __restrict__ wv, const float* __restrict__ wo,
                                                _Float16* __restrict__ wpe) {
  int idx = blockIdx.x * 256 + threadIdx.x;
  if (idx >= 3 * 2 * 16384) return;
  int l = idx / 32768;
  int r = idx % 32768;
  int blk = r >> 14;
  int cout = (r >> 7) & 127;
  int jp = r & 127;
  int j = blk * 128 + jp;
  float val = 0.f;
  if (j < 232) {
    int e = j >> 3, hh = j & 7;
    const float* wvp = wv + (size_t)l * 157 * 128 + (size_t)(128 + e) * 128 + hh * 16;
    const float* wop = wo + (size_t)l * 16384 + (size_t)(hh * 16) * 128 + cout;
#pragma unroll
    for (int d = 0; d < 16; d++) val = fmaf(wvp[d], wop[d * 128], val);
  }
  wpe[(size_t)idx] = f2h(val);
}

// ---------------------------------------------------------------- conv weight prep
__global__ __launch_bounds__(256) void k_prepcw(const float* __restrict__ pw, _Float16* __restrict__ wc) {
  int idx = blockIdx.x * 256 + threadIdx.x;
  if (idx >= 4 * 128 * 128 * 3) return;
  int kt = idx % 3;
  int rest = idx / 3;
  int i = rest % 128; rest /= 128;
  int oo = rest % 128;
  int s = rest / 128;
  wc[(((size_t)s * 3 + kt) * 128 + oo) * 128 + i] = f2h(pw[idx]);
}

// ---------------------------------------------------------------- GEMM helpers: B from GLOBAL
__device__ __forceinline__ void stage_x(const _Float16* __restrict__ src, _Float16* X,
                                        int tid, int rowstride) {
  for (int j = tid; j < 1024; j += 256) {
    int row = j >> 4, seg = (j & 15) * 8;
    *(uint4*)&X[row * 136 + seg] = *(const uint4*)(src + (size_t)row * rowstride + seg);
  }
}
template <bool RESET>
__device__ __forceinline__ void gemm_g(const _Float16* X, const _Float16* __restrict__ Wg,
                                       int wrow, int l16, int quad, f32x4 acc[8]) {
  if (RESET) {
#pragma unroll
    for (int t = 0; t < 8; t++) acc[t] = (f32x4){0.f, 0.f, 0.f, 0.f};
  }
#pragma unroll
  for (int kk = 0; kk < 4; kk++) {
    f16x8 a = *(const f16x8*)&X[(wrow + l16) * 136 + kk * 32 + quad * 8];
#pragma unroll
    for (int t = 0; t < 8; t++) {
      f16x8 b = *(const f16x8*)(Wg + ((size_t)(t * 16 + l16) * 128 + kk * 32 + quad * 8));
      acc[t] = __builtin_amdgcn_mfma_f32_16x16x32_f16(a, b, acc[t], 0, 0, 0);
    }
  }
}

// ---------------------------------------------------------------- layer-0 QKV (+qwk)
__global__ __launch_bounds__(256) void k_qkv(const _Float16* __restrict__ A,
                                             const _Float16* __restrict__ Wqt,
                                             const _Float16* __restrict__ Wkt,
                                             const _Float16* __restrict__ Wvt,
                                             const _Float16* __restrict__ Wqk0,
                                             const _Float16* __restrict__ Wqk1,
                                             _Float16* __restrict__ q, _Float16* __restrict__ hk,
                                             _Float16* __restrict__ hv, _Float16* __restrict__ qkw) {
  __shared__ _Float16 X[64 * 136];
  int tid = threadIdx.x, r0 = blockIdx.x * 64;
  int lane = tid & 63, quad = lane >> 4, l16 = lane & 15, wrow = (tid >> 6) * 16;
  stage_x(A + (size_t)r0 * 128, X, tid, 128);
  __syncthreads();
  const _Float16* wts[5] = {Wqt, Wkt, Wvt, Wqk0, Wqk1};
  f32x4 acc[8];
  for (int w = 0; w < 5; w++) {
    gemm_g<true>(X, wts[w], wrow, l16, quad, acc);
#pragma unroll
    for (int t = 0; t < 8; t++) {
      int col = t * 16 + l16;
#pragma unroll
      for (int r = 0; r < 4; r++) {
        float v = acc[t][r];
        int rowg = r0 + wrow + quad * 4 + r;
        if (w < 3) {
          _Float16* C = (w == 0) ? q : (w == 1) ? hk : hv;
          C[(size_t)rowg * 128 + col] = f2h(v);
        } else {
          qkw[(size_t)rowg * 256 + (w - 3) * 128 + col] = f2h(v);
        }
      }
    }
  }
}

// ---------------------------------------------------------------- fused o-proj(+pe) + residual + MLP (+ next QKV+qwk)
__global__ __launch_bounds__(256) void k_post(const _Float16* __restrict__ o,
                                              const _Float16* __restrict__ pe_g,
                                              _Float16* __restrict__ h,
                                              const _Float16* __restrict__ Wot,
                                              const _Float16* __restrict__ Wpe0,
                                              const _Float16* __restrict__ Wpe1,
                                              const _Float16* __restrict__ W1t, const float* __restrict__ B1,
                                              const _Float16* __restrict__ W2t, const float* __restrict__ B2,
                                              const _Float16* __restrict__ W3t, const float* __restrict__ B3,
                                              const _Float16* __restrict__ Wqt,
                                              const _Float16* __restrict__ Wkt,
                                              const _Float16* __restrict__ Wvt,
                                              const _Float16* __restrict__ Wqk0,
                                              const _Float16* __restrict__ Wqk1,
                                              _Float16* __restrict__ qo, _Float16* __restrict__ hko,
                                              _Float16* __restrict__ hvo, _Float16* __restrict__ qkwo,
                                              int do_qkv) {
  __shared__ _Float16 X[64 * 136];
  int tid = threadIdx.x, r0 = blockIdx.x * 64;
  int lane = tid & 63, quad = lane >> 4, l16 = lane & 15, wrow = (tid >> 6) * 16;
  f32x4 acc[8], hres[8];
  stage_x(o + (size_t)r0 * 128, X, tid, 128);
  __syncthreads();
  gemm_g<true>(X, Wot, wrow, l16, quad, acc);
  const _Float16* wpes[2] = {Wpe0, Wpe1};
#pragma unroll 1
  for (int blk = 0; blk < 2; blk++) {
    __syncthreads();
    stage_x(pe_g + (size_t)r0 * 256 + blk * 128, X, tid, 256);
    __syncthreads();
    gemm_g<false>(X, wpes[blk], wrow, l16, quad, acc);
  }
#pragma unroll
  for (int t = 0; t < 8; t++) {
    int col = t * 16 + l16;
#pragma unroll
    for (int r = 0; r < 4; r++)
      hres[t][r] = acc[t][r] + (float)h[(size_t)(r0 + wrow + quad * 4 + r) * 128 + col];
  }
  __syncthreads();
#pragma unroll
  for (int t = 0; t < 8; t++) {
    int col = t * 16 + l16;
#pragma unroll
    for (int r = 0; r < 4; r++)
      X[(wrow + quad * 4 + r) * 136 + col] = f2h(hres[t][r]);
  }
  __syncthreads();
  gemm_g<true>(X, W1t, wrow, l16, quad, acc);
  __syncthreads();
#pragma unroll
  for (int t = 0; t < 8; t++) {
    int col = t * 16 + l16; float bv = B1[col];
#pragma unroll
    for (int r = 0; r < 4; r++)
      X[(wrow + quad * 4 + r) * 136 + col] = f2h(fmaxf(acc[t][r] + bv, 0.f));
  }
  __syncthreads();
  gemm_g<true>(X, W2t, wrow, l16, quad, acc);
  __syncthreads();
#pragma unroll
  for (int t = 0; t < 8; t++) {
    int col = t * 16 + l16; float bv = B2[col];
#pragma unroll
    for (int r = 0; r < 4; r++)
      X[(wrow + quad * 4 + r) * 136 + col] = f2h(fmaxf(acc[t][r] + bv, 0.f));
  }
  __syncthreads();
  gemm_g<true>(X, W3t, wrow, l16, quad, acc);
  __syncthreads();
#pragma unroll
  for (int t = 0; t < 8; t++) {
    int col = t * 16 + l16; float bv = B3[col];
#pragma unroll
    for (int r = 0; r < 4; r++) {
      float v = hres[t][r] + acc[t][r] + bv;
      h[(size_t)(r0 + wrow + quad * 4 + r) * 128 + col] = f2h(v);
      if (do_qkv) X[(wrow + quad * 4 + r) * 136 + col] = f2h(v);
    }
  }
  if (!do_qkv) return;
  __syncthreads();
  const _Float16* wts[5] = {Wqt, Wkt, Wvt, Wqk0, Wqk1};
  for (int w = 0; w < 5; w++) {
    gemm_g<true>(X, wts[w], wrow, l16, quad, acc);
#pragma unroll
    for (int t = 0; t < 8; t++) {
      int col = t * 16 + l16;
#pragma unroll
      for (int r = 0; r < 4; r++) {
        float v = acc[t][r];
        int rowg = r0 + wrow + quad * 4 + r;
        if (w < 3) {
          _Float16* C = (w == 0) ? qo : (w == 1) ? hko : hvo;
          C[(size_t)rowg * 128 + col] = f2h(v);
        } else {
          qkwo[(size_t)rowg * 256 + (w - 3) * 128 + col] = f2h(v);
        }
      }
    }
  }
}

// ---------------------------------------------------------------- attention core: vectorized LDS
__global__ __launch_bounds__(256) void k_attn(const _Float16* __restrict__ q,
                                              const _Float16* __restrict__ hk,
                                              const _Float16* __restrict__ hv,
                                              const int* __restrict__ nbr,
                                              const _Float16* __restrict__ edge,
                                              const _Float16* __restrict__ qkw,
                                              _Float16* __restrict__ o,
                                              _Float16* __restrict__ pe_g) {
  __shared__ float elL[4][15 * ELP];
  __shared__ float etL[4][32 * ETP];
  __shared__ float plL[4][8 * PLP];
  __shared__ int nbL[4][16];
  int tid = threadIdx.x, wave = tid >> 6, lane = tid & 63;
  float* el = elL[wave]; float* et = etL[wave]; float* pl = plL[wave];
  int* nbl = nbL[wave];
  int h8 = lane & 7, k2 = lane >> 3, c2 = lane * 2, h5 = lane >> 3;
  int kst = lane >> 2, gst = lane & 3;
  if (lane < 32) et[lane * ETP + 15] = 0.f;   // k=15 column, never staged
  int n0 = (blockIdx.x * 4 + wave) * APW;
#pragma unroll 1
  for (int ni = 0; ni < APW; ni++) {
    int n = n0 + ni;
    // ---- P0: stage edge both ways, nbr; qwk+q into regs
    if (lane < 60) {
      f16x8 ev = *(const f16x8*)(edge + ((size_t)n * 15 + kst) * 32 + gst * 8);
      float e0 = (float)ev[0], e1 = (float)ev[1], e2 = (float)ev[2], e3 = (float)ev[3];
      float e4 = (float)ev[4], e5 = (float)ev[5], e6 = (float)ev[6], e7 = (float)ev[7];
      *(f32x4*)&el[kst * ELP + gst * 8]     = (f32x4){e0, e1, e2, e3};
      *(f32x4*)&el[kst * ELP + gst * 8 + 4] = (f32x4){e4, e5, e6, e7};
      int eb = gst * 8;
      et[(eb + 0) * ETP + kst] = e0; et[(eb + 1) * ETP + kst] = e1;
      et[(eb + 2) * ETP + kst] = e2; et[(eb + 3) * ETP + kst] = e3;
      et[(eb + 4) * ETP + kst] = e4; et[(eb + 5) * ETP + kst] = e5;
      et[(eb + 6) * ETP + kst] = e6; et[(eb + 7) * ETP + kst] = e7;
    }
    if (lane < 15) nbl[lane] = nbr[(size_t)n * NNBR + lane];
    const _Float16* qs = qkw + (size_t)n * 256 + h8 * 32;
    f16x8 w0 = *(const f16x8*)qs, w1 = *(const f16x8*)(qs + 8);
    f16x8 w2 = *(const f16x8*)(qs + 16), w3 = *(const f16x8*)(qs + 24);
    float qw[32];
#pragma unroll
    for (int d = 0; d < 8; d++) {
      qw[d] = (float)w0[d]; qw[8 + d] = (float)w1[d];
      qw[16 + d] = (float)w2[d]; qw[24 + d] = (float)w3[d];
    }
    const _Float16* qp = q + (size_t)n * 128 + h8 * 16;
    f16x8 qa = *(const f16x8*)qp, qb = *(const f16x8*)(qp + 8);
    float q16[16];
#pragma unroll
    for (int d = 0; d < 8; d++) { q16[d] = (float)qa[d]; q16[8 + d] = (float)qb[d]; }
    CBAR();
    // ---- P1: logits
#pragma unroll
    for (int p = 0; p < 2; p++) {
      int k = k2 + p * 8;
      if (k < 15) {
        int m = nbl[k];
        const _Float16* hkp = hk + (size_t)m * 128 + h8 * 16;
        f16x8 ha = *(const f16x8*)hkp, hb = *(const f16x8*)(hkp + 8);
        float dot = 0.f;
#pragma unroll
        for (int d = 0; d < 8; d++) dot = fmaf(q16[d], (float)ha[d], dot);
#pragma unroll
        for (int d = 0; d < 8; d++) dot = fmaf(q16[8 + d], (float)hb[d], dot);
        float ep = 0.f;
#pragma unroll
        for (int c = 0; c < 8; c++) {
          f32x4 e4 = *(const f32x4*)&el[k * ELP + c * 4];
          ep = fmaf(e4[0], qw[c * 4 + 0], ep);
          ep = fmaf(e4[1], qw[c * 4 + 1], ep);
          ep = fmaf(e4[2], qw[c * 4 + 2], ep);
          ep = fmaf(e4[3], qw[c * 4 + 3], ep);
        }
        pl[h8 * PLP + k] = fmaf(0.25f, dot, ep);
      } else {
        pl[h8 * PLP + 15] = -1e30f;
      }
    }
    CBAR();
    // ---- P2: softmax per head
    if (lane < 8) {
      float v[16];
      *(f32x4*)&v[0]  = *(const f32x4*)&pl[lane * PLP + 0];
      *(f32x4*)&v[4]  = *(const f32x4*)&pl[lane * PLP + 4];
      *(f32x4*)&v[8]  = *(const f32x4*)&pl[lane * PLP + 8];
      *(f32x4*)&v[12] = *(const f32x4*)&pl[lane * PLP + 12];
      float mx = v[0];
#pragma unroll
      for (int i = 1; i < 15; i++) mx = fmaxf(mx, v[i]);
      float s = 0.f;
#pragma unroll
      for (int i = 0; i < 16; i++) { v[i] = __expf(v[i] - mx); s += v[i]; }
      float inv = 1.f / s;
#pragma unroll
      for (int i = 0; i < 16; i++) v[i] *= inv;
      *(f32x4*)&pl[lane * PLP + 0]  = *(const f32x4*)&v[0];
      *(f32x4*)&pl[lane * PLP + 4]  = *(const f32x4*)&v[4];
      *(f32x4*)&pl[lane * PLP + 8]  = *(const f32x4*)&v[8];
      *(f32x4*)&pl[lane * PLP + 12] = *(const f32x4*)&v[12];
    }
    CBAR();
    // ---- P3: pe[e*8+h]
    _Float16* peo = pe_g + (size_t)n * 256;
#pragma unroll
    for (int p = 0; p < 4; p++) {
      int j = p * 64 + lane;
      float s = 0.f;
      if (j < 232) {
        int e = j >> 3, hh = j & 7;
        f32x4 p0 = *(const f32x4*)&pl[hh * PLP + 0];
        f32x4 p1 = *(const f32x4*)&pl[hh * PLP + 4];
        f32x4 p2 = *(const f32x4*)&pl[hh * PLP + 8];
        f32x4 p3 = *(const f32x4*)&pl[hh * PLP + 12];
        f32x4 t0 = *(const f32x4*)&et[e * ETP + 0];
        f32x4 t1 = *(const f32x4*)&et[e * ETP + 4];
        f32x4 t2 = *(const f32x4*)&et[e * ETP + 8];
        f32x4 t3 = *(const f32x4*)&et[e * ETP + 12];
        s = p0[0]*t0[0] + p0[1]*t0[1] + p0[2]*t0[2] + p0[3]*t0[3]
          + p1[0]*t1[0] + p1[1]*t1[1] + p1[2]*t1[2] + p1[3]*t1[3]
          + p2[0]*t2[0] + p2[1]*t2[1] + p2[2]*t2[2] + p2[3]*t2[3]
          + p3[0]*t3[0] + p3[1]*t3[1] + p3[2]*t3[2] + p3[3]*t3[3];
      }
      peo[j] = f2h(s);
    }
    // ---- P4: o_node channels
    float pk[16];
    *(f32x4*)&pk[0]  = *(const f32x4*)&pl[h5 * PLP + 0];
    *(f32x4*)&pk[4]  = *(const f32x4*)&pl[h5 * PLP + 4];
    *(f32x4*)&pk[8]  = *(const f32x4*)&pl[h5 * PLP + 8];
    *(f32x4*)&pk[12] = *(const f32x4*)&pl[h5 * PLP + 12];
    float ox = 0.f, oy = 0.f;
#pragma unroll
    for (int k = 0; k < 15; k++) {
      int m = nbl[k];
      f16x2 hh = *(const f16x2*)(hv + (size_t)m * 128 + c2);
      ox = fmaf(pk[k], (float)hh[0], ox);
      oy = fmaf(pk[k], (float)hh[1], oy);
    }
    *(f16x2*)(o + (size_t)n * 128 + c2) = (f16x2){f2h(ox), f2h(oy)};
    CBAR();
  }
}

// ---------------------------------------------------------------- MFMA conv+leaky+residual+maxpool2
__global__ __launch_bounds__(256) void k_convpool_m(const _Float16* __restrict__ x,
                                                    const _Float16* __restrict__ Wc,
                                                    const float* __restrict__ bias,
                                                    _Float16* __restrict__ outp, int Tin) {
  __shared__ _Float16 Xs[66 * 136];
  int tid = threadIdx.x;
  int b = blockIdx.y;
  int t0 = blockIdx.x * 64;
  for (int j = tid; j < 66 * 16; j += 256) {
    int row = j >> 4, seg = (j & 15) * 8;
    int t = t0 - 1 + row;
    uint4 v = {0u, 0u, 0u, 0u};
    if (t >= 0 && t < Tin) v = *(const uint4*)(x + ((size_t)b * Tin + t) * 128 + seg);
    *(uint4*)&Xs[row * 136 + seg] = v;
  }
  __syncthreads();
  int lane = tid & 63, quad = lane >> 4, l16 = lane & 15, wrow = (tid >> 6) * 16;
  f32x4 acc[8];
#pragma unroll
  for (int t = 0; t < 8; t++) acc[t] = (f32x4){0.f, 0.f, 0.f, 0.f};
  for (int kt = 0; kt < 3; kt++) {
    const _Float16* Wt = Wc + (size_t)kt * 16384;
#pragma unroll
    for (int kk = 0; kk < 4; kk++) {
      f16x8 a = *(const f16x8*)&Xs[(wrow + l16 + kt) * 136 + kk * 32 + quad * 8];
#pragma unroll
      for (int t = 0; t < 8; t++) {
        f16x8 bfr = *(const f16x8*)(Wt + ((size_t)(t * 16 + l16) * 128 + kk * 32 + quad * 8));
        acc[t] = __builtin_amdgcn_mfma_f32_16x16x32_f16(a, bfr, acc[t], 0, 0, 0);
      }
    }
  }
  int Tout = Tin >> 1;
#pragma unroll
  for (int t = 0; t < 8; t++) {
    int col = t * 16 + l16;
    float bv = bias[col];
#pragma unroll
    for (int rp = 0; rp < 2; rp++) {
      int rl0 = wrow + quad * 4 + rp * 2;
      float y0 = acc[t][rp * 2] + bv;
      float y1 = acc[t][rp * 2 + 1] + bv;
      float z0 = (float)Xs[(rl0 + 1) * 136 + col] + (y0 >= 0.f ? y0 : 0.01f * y0);
      float z1 = (float)Xs[(rl0 + 2) * 136 + col] + (y1 >= 0.f ? y1 : 0.01f * y1);
      outp[((size_t)b * Tout + ((t0 + rl0) >> 1)) * 128 + col] = f2h(fmaxf(z0, z1));
    }
  }
}

// ---------------------------------------------------------------- final reduce
__global__ __launch_bounds__(128) void k_final(const _Float16* __restrict__ x,
                                               const float* __restrict__ ew,
                                               const float* __restrict__ ebb,
                                               float* __restrict__ outp) {
  int b = blockIdx.x, cc = threadIdx.x;
  float s = 0.f;
#pragma unroll
  for (int t = 0; t < 32; t++) s += (float)x[((size_t)b * 32 + t) * 128 + cc];
  float v = s * ew[cc];
#pragma unroll
  for (int m = 1; m < 64; m <<= 1) v += __shfl_xor(v, m);
  __shared__ float red[2];
  if ((cc & 63) == 0) red[cc >> 6] = v;
  __syncthreads();
  if (cc == 0) outp[b] = red[0] + red[1] + ebb[0];
}

// ---------------------------------------------------------------- launch
extern "C" void kernel_launch(void* const* d_in, const int* in_sizes, int n_in,
                              void* d_out, int out_size, void* d_ws, size_t ws_size,
                              hipStream_t stream) {
  (void)in_sizes; (void)n_in; (void)out_size; (void)ws_size;
  const float* tert    = (const float*)d_in[0];
  const float* noise   = (const float*)d_in[3];
  const float* embed_w = (const float*)d_in[4];
  const float* embed_b = (const float*)d_in[5];
  const float* wq = (const float*)d_in[6];
  const float* wk = (const float*)d_in[7];
  const float* wv = (const float*)d_in[8];
  const float* wo = (const float*)d_in[9];
  const float* w1 = (const float*)d_in[10];
  const float* b1 = (const float*)d_in[11];
  const float* w2 = (const float*)d_in[12];
  const float* b2 = (const float*)d_in[13];
  const float* w3 = (const float*)d_in[14];
  const float* b3 = (const float*)d_in[15];
  const float* pw = (const float*)d_in[16];
  const float* pb = (const float*)d_in[17];
  const float* ew = (const float*)d_in[18];
  const float* eb = (const float*)d_in[19];
  float* outp = (float*)d_out;

  char* W = (char*)d_ws;
  float* pos  = (float*)W;        W += 393216;     // N*3 f32
  float* R    = (float*)W;        W += 1179648;    // N*9 f32
  int*   nbr  = (int*)W;          W += 1966080;    // N*15 i32
  _Float16* edge = (_Float16*)W;  W += 31457280;   // N*15*32 f16
  _Float16* h    = (_Float16*)W;  W += 8388608;    // N*128 f16
  _Float16* q    = (_Float16*)W;  W += 8388608;
  _Float16* hk   = (_Float16*)W;  W += 8388608;
  _Float16* hv   = (_Float16*)W;  W += 8388608;
  _Float16* o    = (_Float16*)W;  W += 8388608;
  _Float16* qkw_g = (_Float16*)W; W += 16777216;   // N*256 f16
  _Float16* pe_g  = (_Float16*)W; W += 16777216;   // N*256 f16
  _Float16* xa   = (_Float16*)W;  W += 4194304;    // B*256*128 f16
  _Float16* xb   = (_Float16*)W;  W += 2097152;    // B*128*128 f16
  _Float16* wbt  = (_Float16*)W;  W += 688128;     // 21*16384 f16
  _Float16* wqk  = (_Float16*)W;  W += 196608;     // 3*2*16384 f16
  _Float16* wpe  = (_Float16*)W;  W += 196608;     // 3*2*16384 f16
  _Float16* wct  = (_Float16*)W;  W += 393216;     // 12*16384 f16

  k_frames<<<128, 256, 0, stream>>>(tert, pos, R);
  k_knn<<<8192, 256, 0, stream>>>(pos, noise, nbr);
  k_edge<<<1920, 256, 0, stream>>>(pos, R, nbr, edge);
  k_hinit<<<512, 256, 0, stream>>>(embed_w, embed_b, h);
  k_prepw<<<1344, 256, 0, stream>>>(wq, wk, wv, wo, w1, w2, w3, wbt);
  k_prepqk<<<384, 256, 0, stream>>>(wq, wk, wqk);
  k_preppe<<<384, 256, 0, stream>>>(wv, wo, wpe);
  k_prepcw<<<768, 256, 0, stream>>>(pw, wct);

  const _Float16* wt[3][7];
  for (int l = 0; l < 3; l++)
    for (int w = 0; w < 7; w++) wt[l][w] = wbt + (size_t)(l * 7 + w) * 16384;
  const _Float16* wqk_l[3][2];
  const _Float16* wpe_l[3][2];
  for (int l = 0; l < 3; l++)
    for (int bk = 0; bk < 2; bk++) {
      wqk_l[l][bk] = wqk + (size_t)(l * 2 + bk) * 16384;
      wpe_l[l][bk] = wpe + (size_t)(l * 2 + bk) * 16384;
    }

  k_qkv<<<512, 256, 0, stream>>>(h, wt[0][0], wt[0][1], wt[0][2],
                                 wqk_l[0][0], wqk_l[0][1], q, hk, hv, qkw_g);
  for (int l = 0; l < 3; l++) {
    k_attn<<<1024, 256, 0, stream>>>(q, hk, hv, nbr, edge, qkw_g, o, pe_g);
    int nl = l + 1;
    int do_qkv = (nl < 3) ? 1 : 0;
    k_post<<<512, 256, 0, stream>>>(o, pe_g, h, wt[l][3],
                                    wpe_l[l][0], wpe_l[l][1],
                                    wt[l][4], b1 + l * 128,
                                    wt[l][5], b2 + l * 128,
                                    wt[l][6], b3 + l * 128,
                                    do_qkv ? wt[nl][0] : nullptr,
                                    do_qkv ? wt[nl][1] : nullptr,
                                    do_qkv ? wt[nl][2] : nullptr,
                                    do_qkv ? wqk_l[nl][0] : nullptr,
                                    do_qkv ? wqk_l[nl][1] : nullptr,
                                    q, hk, hv, qkw_g, do_qkv);
  }

  k_convpool_m<<<dim3(8, 64), 256, 0, stream>>>(h,  wct + 0 * 49152, pb + 0,   xa, 512);
  k_convpool_m<<<dim3(4, 64), 256, 0, stream>>>(xa, wct + 1 * 49152, pb + 128, xb, 256);
  k_convpool_m<<<dim3(2, 64), 256, 0, stream>>>(xb, wct + 2 * 49152, pb + 256, xa, 128);
  k_convpool_m<<<dim3(1, 64), 256, 0, stream>>>(xa, wct + 3 * 49152, pb + 384, xb, 64);
  k_final<<<64, 128, 0, stream>>>(xb, ew, eb, outp);
}

// Round 9
// 555.012 us; speedup vs baseline: 1.3876x; 1.3876x over previous
//
#include <hip/hip_runtime.h>
#include <math.h>

#define N_TOT 32768
#define NNBR 15
#define APW 8
#define ELP 36
#define ETP 20
#define PLP 20

typedef __attribute__((ext_vector_type(8))) _Float16 f16x8;
typedef __attribute__((ext_vector_type(2))) _Float16 f16x2;
typedef __attribute__((ext_vector_type(4))) float f32x4;

#define CBAR() __asm__ volatile("" ::: "memory")

__device__ __forceinline__ _Float16 f2h(float x) { return (_Float16)x; }

// ---------------------------------------------------------------- frames
__global__ __launch_bounds__(256) void k_frames(const float* __restrict__ tert,
                                                float* __restrict__ pos,
                                                float* __restrict__ R) {
  int n = blockIdx.x * 256 + threadIdx.x;
  if (n >= N_TOT) return;
  float px = tert[n * 9 + 3], py = tert[n * 9 + 4], pz = tert[n * 9 + 5];
  pos[n * 3 + 0] = px; pos[n * 3 + 1] = py; pos[n * 3 + 2] = pz;

  int i0 = (n > 0) ? (n - 1) : 0;
  int i1 = (n < N_TOT - 1) ? n : (N_TOT - 2);

  float ax = tert[(i0 + 1) * 9 + 3] - tert[i0 * 9 + 3];
  float ay = tert[(i0 + 1) * 9 + 4] - tert[i0 * 9 + 4];
  float az = tert[(i0 + 1) * 9 + 5] - tert[i0 * 9 + 5];
  float il = 1.f / (sqrtf(ax * ax + ay * ay + az * az) + 1e-8f);
  float ux = ax * il, uy = ay * il, uz = az * il;

  float cx = tert[(i1 + 1) * 9 + 3] - tert[i1 * 9 + 3];
  float cy = tert[(i1 + 1) * 9 + 4] - tert[i1 * 9 + 4];
  float cz = tert[(i1 + 1) * 9 + 5] - tert[i1 * 9 + 5];
  il = 1.f / (sqrtf(cx * cx + cy * cy + cz * cz) + 1e-8f);
  float vx = cx * il, vy = cy * il, vz = cz * il;

  float bx = ux - vx, by = uy - vy, bz = uz - vz;
  il = 1.f / (sqrtf(bx * bx + by * by + bz * bz) + 1e-8f);
  bx *= il; by *= il; bz *= il;

  float nx = uy * vz - uz * vy;
  float ny = uz * vx - ux * vz;
  float nz = ux * vy - uy * vx;
  il = 1.f / (sqrtf(nx * nx + ny * ny + nz * nz) + 1e-8f);
  nx *= il; ny *= il; nz *= il;

  float ex = by * nz - bz * ny;
  float ey = bz * nx - bx * nz;
  float ez = bx * ny - by * nx;

  float* Rn = R + (size_t)n * 9;
  Rn[0] = bx; Rn[1] = nx; Rn[2] = ex;
  Rn[3] = by; Rn[4] = ny; Rn[5] = ey;
  Rn[6] = bz; Rn[7] = nz; Rn[8] = ez;
}

// ---------------------------------------------------------------- kNN (round-6 version: u64 keys + winner rescan)
__global__ __launch_bounds__(256) void k_knn(const float* __restrict__ pos,
                                             const float* __restrict__ noise,
                                             int* __restrict__ nbr) {
  int wave = threadIdx.x >> 6, lane = threadIdx.x & 63;
  int row = blockIdx.x * 4 + wave;
  int b = row >> 9;
  float pix = pos[row * 3 + 0], piy = pos[row * 3 + 1], piz = pos[row * 3 + 2];
  const float* nrow = noise + (size_t)row * 512;
  const float* pb = pos + (size_t)b * 512 * 3;
  unsigned long long key[8];
#pragma unroll
  for (int jj = 0; jj < 8; jj++) {
    int j = lane + jj * 64;
    float dx = pb[j * 3 + 0] - pix;
    float dy = pb[j * 3 + 1] - piy;
    float dz = pb[j * 3 + 2] - piz;
    float c = -sqrtf(dx * dx + dy * dy + dz * dz) + 3.f * nrow[j];
    unsigned u = __float_as_uint(c);
    unsigned s = u ^ (unsigned)(((int)u >> 31) | (int)0x80000000);
    key[jj] = ((unsigned long long)s << 9) | (unsigned)(511 - j);
  }
  unsigned long long best = key[0];
#pragma unroll
  for (int jj = 1; jj < 8; jj++) best = key[jj] > best ? key[jj] : best;
  int jmine = 0;
#pragma unroll 1
  for (int it = 0; it < NNBR; it++) {
    unsigned long long g = best;
#pragma unroll
    for (int m = 1; m < 64; m <<= 1) {
      unsigned long long og = __shfl_xor(g, m);
      g = og > g ? og : g;
    }
    int j = 511 - (int)(g & 511ull);
    if (lane == it) jmine = j;
    if ((j & 63) == lane) {
      int slot = j >> 6;
#pragma unroll
      for (int jj = 0; jj < 8; jj++) if (slot == jj) key[jj] = 0ull;
      best = key[0];
#pragma unroll
      for (int jj = 1; jj < 8; jj++) best = key[jj] > best ? key[jj] : best;
    }
  }
  if (lane < NNBR) nbr[(size_t)row * NNBR + lane] = b * 512 + jmine;
}

// ---------------------------------------------------------------- edge features (fp16, 32-padded, vector stores)
__global__ __launch_bounds__(256) void k_edge(const float* __restrict__ pos,
                                              const float* __restrict__ R,
                                              const int* __restrict__ nbr,
                                              _Float16* __restrict__ edge) {
  int idx = blockIdx.x * 256 + threadIdx.x;
  if (idx >= N_TOT * NNBR) return;
  int n = idx / NNBR;
  int m = nbr[idx];
  float dx = pos[m * 3 + 0] - pos[n * 3 + 0];
  float dy = pos[m * 3 + 1] - pos[n * 3 + 1];
  float dz = pos[m * 3 + 2] - pos[n * 3 + 2];
  float d = sqrtf(dx * dx + dy * dy + dz * dz);
  _Float16 eb[32];
#pragma unroll
  for (int j = 0; j < 16; j++) {
    float mu = (20.f / 15.f) * (float)j;
    float t = (d - mu) * 0.8f;
    eb[j] = f2h(__expf(-t * t));
  }
  float inv = 1.f / (d + 1e-8f);
  float ux = dx * inv, uy = dy * inv, uz = dz * inv;
  float Rn[9], Rm[9];
#pragma unroll
  for (int j = 0; j < 9; j++) { Rn[j] = R[(size_t)n * 9 + j]; Rm[j] = R[(size_t)m * 9 + j]; }
#pragma unroll
  for (int cc = 0; cc < 3; cc++)
    eb[16 + cc] = f2h(Rn[0 * 3 + cc] * ux + Rn[1 * 3 + cc] * uy + Rn[2 * 3 + cc] * uz);
#pragma unroll
  for (int cc = 0; cc < 3; cc++)
#pragma unroll
    for (int dd = 0; dd < 3; dd++)
      eb[19 + cc * 3 + dd] = f2h(Rn[0 * 3 + cc] * Rm[0 * 3 + dd] +
                                 Rn[1 * 3 + cc] * Rm[1 * 3 + dd] +
                                 Rn[2 * 3 + cc] * Rm[2 * 3 + dd]);
  eb[28] = f2h((float)(m - n));
  eb[29] = (_Float16)0.f; eb[30] = (_Float16)0.f; eb[31] = (_Float16)0.f;
  _Float16* e = edge + (size_t)idx * 32;
#pragma unroll
  for (int v = 0; v < 4; v++)
    *(uint4*)(e + v * 8) = *(const uint4*)(&eb[v * 8]);
}

// ---------------------------------------------------------------- h init (fp16)
__global__ __launch_bounds__(256) void k_hinit(const float* __restrict__ ew,
                                               const float* __restrict__ ebias,
                                               _Float16* __restrict__ h) {
  __shared__ float hv[128];
  int tid = threadIdx.x;
  if (tid < 128) {
    float s = ebias[tid];
#pragma unroll
    for (int i = 0; i < 27; i++) s += ew[i * 128 + tid];
    hv[tid] = s;
  }
  __syncthreads();
  size_t total = (size_t)N_TOT * 128;
  for (size_t j = (size_t)blockIdx.x * 256 + tid; j < total; j += (size_t)gridDim.x * 256)
    h[j] = f2h(hv[j & 127]);
}

// ---------------------------------------------------------------- dense weight prep: fp32 [k][n] -> fp16 [n][k]
__global__ __launch_bounds__(256) void k_prepw(const float* __restrict__ wq, const float* __restrict__ wk,
                                               const float* __restrict__ wv, const float* __restrict__ wo,
                                               const float* __restrict__ w1, const float* __restrict__ w2,
                                               const float* __restrict__ w3, _Float16* __restrict__ wbt) {
  int idx = blockIdx.x * 256 + threadIdx.x;
  if (idx >= 3 * 7 * 16384) return;
  int l = idx / (7 * 16384);
  int r = idx % (7 * 16384);
  int w = r / 16384;
  int e = r % 16384;
  int k = e >> 7, n = e & 127;
  float val;
  switch (w) {
    case 0: val = wq[(size_t)l * 16384 + e]; break;
    case 1: val = wk[(size_t)l * 157 * 128 + e]; break;
    case 2: val = wv[(size_t)l * 157 * 128 + e]; break;
    case 3: val = wo[(size_t)l * 16384 + e]; break;
    case 4: val = w1[(size_t)l * 16384 + e]; break;
    case 5: val = w2[(size_t)l * 16384 + e]; break;
    default: val = w3[(size_t)l * 16384 + e]; break;
  }
  wbt[(size_t)(l * 7 + w) * 16384 + n * 128 + k] = f2h(val);
}

// ---------------------------------------------------------------- Wqk composite (j = h*32+e layout)
__global__ __launch_bounds__(256) void k_prepqk(const float* __restrict__ wq,
                                                const float* __restrict__ wk,
                                                _Float16* __restrict__ wqk) {
  int idx = blockIdx.x * 256 + threadIdx.x;
  if (idx >= 3 * 2 * 16384) return;
  int l = idx / 32768;
  int r = idx % 32768;
  int blk = r >> 14;
  int jp = (r >> 7) & 127;
  int c = r & 127;
  int j = blk * 128 + jp;        // j = h*32 + e
  int hh = j >> 5, e = j & 31;
  float val = 0.f;
  if (e < 29) {
    const float* wqp = wq + (size_t)l * 16384 + (size_t)c * 128 + hh * 16;
    const float* wkp = wk + (size_t)l * 157 * 128 + (size_t)(128 + e) * 128 + hh * 16;
    float s = 0.f;
#pragma unroll
    for (int d = 0; d < 16; d++) s = fmaf(wqp[d], wkp[d], s);
    val = 0.25f * s;
  }
  wqk[(size_t)idx] = f2h(val);
}

// ---------------------------------------------------------------- wpe = Wv_e'' @ Wo (j = e*8+h layout)
__global__ __launch_bounds__(256) void k_preppe(const float* __restrict__ wv, const float* __restrict__ wo,
                                                _Float16* __restrict__ wpe) {
  int idx = blockIdx.x * 256 + threadIdx.x;
  if (idx >= 3 * 2 * 16384) return;
  int l = idx / 32768;
  int r = idx % 32768;
  int blk = r >> 14;
  int cout = (r >> 7) & 127;
  int jp = r & 127;
  int j = blk * 128 + jp;
  float val = 0.f;
  if (j < 232) {
    int e = j >> 3, hh = j & 7;
    const float* wvp = wv + (size_t)l * 157 * 128 + (size_t)(128 + e) * 128 + hh * 16;
    const float* wop = wo + (size_t)l * 16384 + (size_t)(hh * 16) * 128 + cout;
#pragma unroll
    for (int d = 0; d < 16; d++) val = fmaf(wvp[d], wop[d * 128], val);
  }
  wpe[(size_t)idx] = f2h(val);
}

// ---------------------------------------------------------------- conv weight prep
__global__ __launch_bounds__(256) void k_prepcw(const float* __restrict__ pw, _Float16* __restrict__ wc) {
  int idx = blockIdx.x * 256 + threadIdx.x;
  if (idx >= 4 * 128 * 128 * 3) return;
  int kt = idx % 3;
  int rest = idx / 3;
  int i = rest % 128; rest /= 128;
  int oo = rest % 128;
  int s = rest / 128;
  wc[(((size_t)s * 3 + kt) * 128 + oo) * 128 + i] = f2h(pw[idx]);
}

// ---------------------------------------------------------------- GEMM helpers (LDS-staged weights, round-6)
__device__ __forceinline__ void stage_w(const _Float16* __restrict__ W, _Float16* Ws, int tid) {
  for (int j = tid; j < 2048; j += 256) {
    int row = j >> 4, seg = (j & 15) * 8;
    *(uint4*)&Ws[row * 136 + seg] = *(const uint4*)(W + (size_t)row * 128 + seg);
  }
}
__device__ __forceinline__ void stage_x(const _Float16* __restrict__ src, _Float16* X,
                                        int tid, int rowstride) {
  for (int j = tid; j < 1024; j += 256) {
    int row = j >> 4, seg = (j & 15) * 8;
    *(uint4*)&X[row * 136 + seg] = *(const uint4*)(src + (size_t)row * rowstride + seg);
  }
}
template <bool RESET>
__device__ __forceinline__ void gemm_tile_t(const _Float16* X, const _Float16* Ws,
                                            int wrow, int l16, int quad, f32x4 acc[8]) {
  if (RESET) {
#pragma unroll
    for (int t = 0; t < 8; t++) acc[t] = (f32x4){0.f, 0.f, 0.f, 0.f};
  }
#pragma unroll
  for (int kk = 0; kk < 4; kk++) {
    f16x8 a = *(const f16x8*)&X[(wrow + l16) * 136 + kk * 32 + quad * 8];
#pragma unroll
    for (int t = 0; t < 8; t++) {
      f16x8 b = *(const f16x8*)&Ws[(t * 16 + l16) * 136 + kk * 32 + quad * 8];
      acc[t] = __builtin_amdgcn_mfma_f32_16x16x32_f16(a, b, acc[t], 0, 0, 0);
    }
  }
}

// ---------------------------------------------------------------- layer-0 QKV (+qwk)
__global__ __launch_bounds__(256) void k_qkv(const _Float16* __restrict__ A,
                                             const _Float16* __restrict__ Wqt,
                                             const _Float16* __restrict__ Wkt,
                                             const _Float16* __restrict__ Wvt,
                                             const _Float16* __restrict__ Wqk0,
                                             const _Float16* __restrict__ Wqk1,
                                             _Float16* __restrict__ q, _Float16* __restrict__ hk,
                                             _Float16* __restrict__ hv, _Float16* __restrict__ qkw) {
  __shared__ _Float16 X[64 * 136];
  __shared__ _Float16 Ws[128 * 136];
  int tid = threadIdx.x, r0 = blockIdx.x * 64;
  int lane = tid & 63, quad = lane >> 4, l16 = lane & 15, wrow = (tid >> 6) * 16;
  stage_x(A + (size_t)r0 * 128, X, tid, 128);
  const _Float16* wts[5] = {Wqt, Wkt, Wvt, Wqk0, Wqk1};
  f32x4 acc[8];
  for (int w = 0; w < 5; w++) {
    __syncthreads();
    stage_w(wts[w], Ws, tid);
    __syncthreads();
    gemm_tile_t<true>(X, Ws, wrow, l16, quad, acc);
#pragma unroll
    for (int t = 0; t < 8; t++) {
      int col = t * 16 + l16;
#pragma unroll
      for (int r = 0; r < 4; r++) {
        float v = acc[t][r];
        int rowg = r0 + wrow + quad * 4 + r;
        if (w < 3) {
          _Float16* C = (w == 0) ? q : (w == 1) ? hk : hv;
          C[(size_t)rowg * 128 + col] = f2h(v);
        } else {
          qkw[(size_t)rowg * 256 + (w - 3) * 128 + col] = f2h(v);
        }
      }
    }
  }
}

// ---------------------------------------------------------------- fused o-proj(+pe) + residual + MLP (+ next QKV+qwk)
__global__ __launch_bounds__(256) void k_post(const _Float16* __restrict__ o,
                                              const _Float16* __restrict__ pe_g,
                                              _Float16* __restrict__ h,
                                              const _Float16* __restrict__ Wot,
                                              const _Float16* __restrict__ Wpe0,
                                              const _Float16* __restrict__ Wpe1,
                                              const _Float16* __restrict__ W1t, const float* __restrict__ B1,
                                              const _Float16* __restrict__ W2t, const float* __restrict__ B2,
                                              const _Float16* __restrict__ W3t, const float* __restrict__ B3,
                                              const _Float16* __restrict__ Wqt,
                                              const _Float16* __restrict__ Wkt,
                                              const _Float16* __restrict__ Wvt,
                                              const _Float16* __restrict__ Wqk0,
                                              const _Float16* __restrict__ Wqk1,
                                              _Float16* __restrict__ qo, _Float16* __restrict__ hko,
                                              _Float16* __restrict__ hvo, _Float16* __restrict__ qkwo,
                                              int do_qkv) {
  __shared__ _Float16 X[64 * 136];
  __shared__ _Float16 Ws[128 * 136];
  int tid = threadIdx.x, r0 = blockIdx.x * 64;
  int lane = tid & 63, quad = lane >> 4, l16 = lane & 15, wrow = (tid >> 6) * 16;
  f32x4 acc[8], hres[8];
  stage_x(o + (size_t)r0 * 128, X, tid, 128);
  stage_w(Wot, Ws, tid);
  __syncthreads();
  gemm_tile_t<true>(X, Ws, wrow, l16, quad, acc);
  const _Float16* wpes[2] = {Wpe0, Wpe1};
#pragma unroll 1
  for (int blk = 0; blk < 2; blk++) {
    __syncthreads();
    stage_x(pe_g + (size_t)r0 * 256 + blk * 128, X, tid, 256);
    stage_w(wpes[blk], Ws, tid);
    __syncthreads();
    gemm_tile_t<false>(X, Ws, wrow, l16, quad, acc);
  }
#pragma unroll
  for (int t = 0; t < 8; t++) {
    int col = t * 16 + l16;
#pragma unroll
    for (int r = 0; r < 4; r++)
      hres[t][r] = acc[t][r] + (float)h[(size_t)(r0 + wrow + quad * 4 + r) * 128 + col];
  }
  __syncthreads();
#pragma unroll
  for (int t = 0; t < 8; t++) {
    int col = t * 16 + l16;
#pragma unroll
    for (int r = 0; r < 4; r++)
      X[(wrow + quad * 4 + r) * 136 + col] = f2h(hres[t][r]);
  }
  stage_w(W1t, Ws, tid);
  __syncthreads();
  gemm_tile_t<true>(X, Ws, wrow, l16, quad, acc);
  __syncthreads();
#pragma unroll
  for (int t = 0; t < 8; t++) {
    int col = t * 16 + l16; float bv = B1[col];
#pragma unroll
    for (int r = 0; r < 4; r++)
      X[(wrow + quad * 4 + r) * 136 + col] = f2h(fmaxf(acc[t][r] + bv, 0.f));
  }
  stage_w(W2t, Ws, tid);
  __syncthreads();
  gemm_tile_t<true>(X, Ws, wrow, l16, quad, acc);
  __syncthreads();
#pragma unroll
  for (int t = 0; t < 8; t++) {
    int col = t * 16 + l16; float bv = B2[col];
#pragma unroll
    for (int r = 0; r < 4; r++)
      X[(wrow + quad * 4 + r) * 136 + col] = f2h(fmaxf(acc[t][r] + bv, 0.f));
  }
  stage_w(W3t, Ws, tid);
  __syncthreads();
  gemm_tile_t<true>(X, Ws, wrow, l16, quad, acc);
  __syncthreads();
#pragma unroll
  for (int t = 0; t < 8; t++) {
    int col = t * 16 + l16; float bv = B3[col];
#pragma unroll
    for (int r = 0; r < 4; r++) {
      float v = hres[t][r] + acc[t][r] + bv;
      h[(size_t)(r0 + wrow + quad * 4 + r) * 128 + col] = f2h(v);
      if (do_qkv) X[(wrow + quad * 4 + r) * 136 + col] = f2h(v);
    }
  }
  if (!do_qkv) return;
  const _Float16* wts[5] = {Wqt, Wkt, Wvt, Wqk0, Wqk1};
  for (int w = 0; w < 5; w++) {
    __syncthreads();
    stage_w(wts[w], Ws, tid);
    __syncthreads();
    gemm_tile_t<true>(X, Ws, wrow, l16, quad, acc);
#pragma unroll
    for (int t = 0; t < 8; t++) {
      int col = t * 16 + l16;
#pragma unroll
      for (int r = 0; r < 4; r++) {
        float v = acc[t][r];
        int rowg = r0 + wrow + quad * 4 + r;
        if (w < 3) {
          _Float16* C = (w == 0) ? qo : (w == 1) ? hko : hvo;
          C[(size_t)rowg * 128 + col] = f2h(v);
        } else {
          qkwo[(size_t)rowg * 256 + (w - 3) * 128 + col] = f2h(v);
        }
      }
    }
  }
}

// ---------------------------------------------------------------- attention core: vectorized LDS (round-7)
__global__ __launch_bounds__(256) void k_attn(const _Float16* __restrict__ q,
                                              const _Float16* __restrict__ hk,
                                              const _Float16* __restrict__ hv,
                                              const int* __restrict__ nbr,
                                              const _Float16* __restrict__ edge,
                                              const _Float16* __restrict__ qkw,
                                              _Float16* __restrict__ o,
                                              _Float16* __restrict__ pe_g) {
  __shared__ float elL[4][15 * ELP];
  __shared__ float etL[4][32 * ETP];
  __shared__ float plL[4][8 * PLP];
  __shared__ int nbL[4][16];
  int tid = threadIdx.x, wave = tid >> 6, lane = tid & 63;
  float* el = elL[wave]; float* et = etL[wave]; float* pl = plL[wave];
  int* nbl = nbL[wave];
  int h8 = lane & 7, k2 = lane >> 3, c2 = lane * 2, h5 = lane >> 3;
  int kst = lane >> 2, gst = lane & 3;
  if (lane < 32) et[lane * ETP + 15] = 0.f;
  int n0 = (blockIdx.x * 4 + wave) * APW;
#pragma unroll 1
  for (int ni = 0; ni < APW; ni++) {
    int n = n0 + ni;
    if (lane < 60) {
      f16x8 ev = *(const f16x8*)(edge + ((size_t)n * 15 + kst) * 32 + gst * 8);
      float e0 = (float)ev[0], e1 = (float)ev[1], e2 = (float)ev[2], e3 = (float)ev[3];
      float e4 = (float)ev[4], e5 = (float)ev[5], e6 = (float)ev[6], e7 = (float)ev[7];
      *(f32x4*)&el[kst * ELP + gst * 8]     = (f32x4){e0, e1, e2, e3};
      *(f32x4*)&el[kst * ELP + gst * 8 + 4] = (f32x4){e4, e5, e6, e7};
      int ebs = gst * 8;
      et[(ebs + 0) * ETP + kst] = e0; et[(ebs + 1) * ETP + kst] = e1;
      et[(ebs + 2) * ETP + kst] = e2; et[(ebs + 3) * ETP + kst] = e3;
      et[(ebs + 4) * ETP + kst] = e4; et[(ebs + 5) * ETP + kst] = e5;
      et[(ebs + 6) * ETP + kst] = e6; et[(ebs + 7) * ETP + kst] = e7;
    }
    if (lane < 15) nbl[lane] = nbr[(size_t)n * NNBR + lane];
    const _Float16* qs = qkw + (size_t)n * 256 + h8 * 32;
    f16x8 w0 = *(const f16x8*)qs, w1 = *(const f16x8*)(qs + 8);
    f16x8 w2 = *(const f16x8*)(qs + 16), w3 = *(const f16x8*)(qs + 24);
    float qw[32];
#pragma unroll
    for (int d = 0; d < 8; d++) {
      qw[d] = (float)w0[d]; qw[8 + d] = (float)w1[d];
      qw[16 + d] = (float)w2[d]; qw[24 + d] = (float)w3[d];
    }
    const _Float16* qp = q + (size_t)n * 128 + h8 * 16;
    f16x8 qa = *(const f16x8*)qp, qb = *(const f16x8*)(qp + 8);
    float q16[16];
#pragma unroll
    for (int d = 0; d < 8; d++) { q16[d] = (float)qa[d]; q16[8 + d] = (float)qb[d]; }
    CBAR();
#pragma unroll
    for (int p = 0; p < 2; p++) {
      int k = k2 + p * 8;
      if (k < 15) {
        int m = nbl[k];
        const _Float16* hkp = hk + (size_t)m * 128 + h8 * 16;
        f16x8 ha = *(const f16x8*)hkp, hb = *(const f16x8*)(hkp + 8);
        float dot = 0.f;
#pragma unroll
        for (int d = 0; d < 8; d++) dot = fmaf(q16[d], (float)ha[d], dot);
#pragma unroll
        for (int d = 0; d < 8; d++) dot = fmaf(q16[8 + d], (float)hb[d], dot);
        float ep = 0.f;
#pragma unroll
        for (int c = 0; c < 8; c++) {
          f32x4 e4 = *(const f32x4*)&el[k * ELP + c * 4];
          ep = fmaf(e4[0], qw[c * 4 + 0], ep);
          ep = fmaf(e4[1], qw[c * 4 + 1], ep);
          ep = fmaf(e4[2], qw[c * 4 + 2], ep);
          ep = fmaf(e4[3], qw[c * 4 + 3], ep);
        }
        pl[h8 * PLP + k] = fmaf(0.25f, dot, ep);
      } else {
        pl[h8 * PLP + 15] = -1e30f;
      }
    }
    CBAR();
    if (lane < 8) {
      float v[16];
      *(f32x4*)&v[0]  = *(const f32x4*)&pl[lane * PLP + 0];
      *(f32x4*)&v[4]  = *(const f32x4*)&pl[lane * PLP + 4];
      *(f32x4*)&v[8]  = *(const f32x4*)&pl[lane * PLP + 8];
      *(f32x4*)&v[12] = *(const f32x4*)&pl[lane * PLP + 12];
      float mx = v[0];
#pragma unroll
      for (int i = 1; i < 15; i++) mx = fmaxf(mx, v[i]);
      float s = 0.f;
#pragma unroll
      for (int i = 0; i < 16; i++) { v[i] = __expf(v[i] - mx); s += v[i]; }
      float inv = 1.f / s;
#pragma unroll
      for (int i = 0; i < 16; i++) v[i] *= inv;
      *(f32x4*)&pl[lane * PLP + 0]  = *(const f32x4*)&v[0];
      *(f32x4*)&pl[lane * PLP + 4]  = *(const f32x4*)&v[4];
      *(f32x4*)&pl[lane * PLP + 8]  = *(const f32x4*)&v[8];
      *(f32x4*)&pl[lane * PLP + 12] = *(const f32x4*)&v[12];
    }
    CBAR();
    _Float16* peo = pe_g + (size_t)n * 256;
#pragma unroll
    for (int p = 0; p < 4; p++) {
      int j = p * 64 + lane;
      float s = 0.f;
      if (j < 232) {
        int e = j >> 3, hh = j & 7;
        f32x4 p0 = *(const f32x4*)&pl[hh * PLP + 0];
        f32x4 p1 = *(const f32x4*)&pl[hh * PLP + 4];
        f32x4 p2 = *(const f32x4*)&pl[hh * PLP + 8];
        f32x4 p3 = *(const f32x4*)&pl[hh * PLP + 12];
        f32x4 t0 = *(const f32x4*)&et[e * ETP + 0];
        f32x4 t1 = *(const f32x4*)&et[e * ETP + 4];
        f32x4 t2 = *(const f32x4*)&et[e * ETP + 8];
        f32x4 t3 = *(const f32x4*)&et[e * ETP + 12];
        s = p0[0]*t0[0] + p0[1]*t0[1] + p0[2]*t0[2] + p0[3]*t0[3]
          + p1[0]*t1[0] + p1[1]*t1[1] + p1[2]*t1[2] + p1[3]*t1[3]
          + p2[0]*t2[0] + p2[1]*t2[1] + p2[2]*t2[2] + p2[3]*t2[3]
          + p3[0]*t3[0] + p3[1]*t3[1] + p3[2]*t3[2] + p3[3]*t3[3];
      }
      peo[j] = f2h(s);
    }
    float pk[16];
    *(f32x4*)&pk[0]  = *(const f32x4*)&pl[h5 * PLP + 0];
    *(f32x4*)&pk[4]  = *(const f32x4*)&pl[h5 * PLP + 4];
    *(f32x4*)&pk[8]  = *(const f32x4*)&pl[h5 * PLP + 8];
    *(f32x4*)&pk[12] = *(const f32x4*)&pl[h5 * PLP + 12];
    float ox = 0.f, oy = 0.f;
#pragma unroll
    for (int k = 0; k < 15; k++) {
      int m = nbl[k];
      f16x2 hh = *(const f16x2*)(hv + (size_t)m * 128 + c2);
      ox = fmaf(pk[k], (float)hh[0], ox);
      oy = fmaf(pk[k], (float)hh[1], oy);
    }
    *(f16x2*)(o + (size_t)n * 128 + c2) = (f16x2){f2h(ox), f2h(oy)};
    CBAR();
  }
}

// ---------------------------------------------------------------- MFMA conv+leaky+residual+maxpool2 (LDS-staged W)
__global__ __launch_bounds__(256) void k_convpool_m(const _Float16* __restrict__ x,
                                                    const _Float16* __restrict__ Wc,
                                                    const float* __restrict__ bias,
                                                    _Float16* __restrict__ outp, int Tin) {
  __shared__ _Float16 Xs[66 * 136];
  __shared__ _Float16 Ws[128 * 136];
  int tid = threadIdx.x;
  int b = blockIdx.y;
  int t0 = blockIdx.x * 64;
  for (int j = tid; j < 66 * 16; j += 256) {
    int row = j >> 4, seg = (j & 15) * 8;
    int t = t0 - 1 + row;
    uint4 v = {0u, 0u, 0u, 0u};
    if (t >= 0 && t < Tin) v = *(const uint4*)(x + ((size_t)b * Tin + t) * 128 + seg);
    *(uint4*)&Xs[row * 136 + seg] = v;
  }
  int lane = tid & 63, quad = lane >> 4, l16 = lane & 15, wrow = (tid >> 6) * 16;
  f32x4 acc[8];
#pragma unroll
  for (int t = 0; t < 8; t++) acc[t] = (f32x4){0.f, 0.f, 0.f, 0.f};
  for (int kt = 0; kt < 3; kt++) {
    __syncthreads();
    stage_w(Wc + (size_t)kt * 16384, Ws, tid);
    __syncthreads();
#pragma unroll
    for (int kk = 0; kk < 4; kk++) {
      f16x8 a = *(const f16x8*)&Xs[(wrow + l16 + kt) * 136 + kk * 32 + quad * 8];
#pragma unroll
      for (int t = 0; t < 8; t++) {
        f16x8 bfr = *(const f16x8*)&Ws[(t * 16 + l16) * 136 + kk * 32 + quad * 8];
        acc[t] = __builtin_amdgcn_mfma_f32_16x16x32_f16(a, bfr, acc[t], 0, 0, 0);
      }
    }
  }
  int Tout = Tin >> 1;
#pragma unroll
  for (int t = 0; t < 8; t++) {
    int col = t * 16 + l16;
    float bv = bias[col];
#pragma unroll
    for (int rp = 0; rp < 2; rp++) {
      int rl0 = wrow + quad * 4 + rp * 2;
      float y0 = acc[t][rp * 2] + bv;
      float y1 = acc[t][rp * 2 + 1] + bv;
      float z0 = (float)Xs[(rl0 + 1) * 136 + col] + (y0 >= 0.f ? y0 : 0.01f * y0);
      float z1 = (float)Xs[(rl0 + 2) * 136 + col] + (y1 >= 0.f ? y1 : 0.01f * y1);
      outp[((size_t)b * Tout + ((t0 + rl0) >> 1)) * 128 + col] = f2h(fmaxf(z0, z1));
    }
  }
}

// ---------------------------------------------------------------- final reduce
__global__ __launch_bounds__(128) void k_final(const _Float16* __restrict__ x,
                                               const float* __restrict__ ew,
                                               const float* __restrict__ ebb,
                                               float* __restrict__ outp) {
  int b = blockIdx.x, cc = threadIdx.x;
  float s = 0.f;
#pragma unroll
  for (int t = 0; t < 32; t++) s += (float)x[((size_t)b * 32 + t) * 128 + cc];
  float v = s * ew[cc];
#pragma unroll
  for (int m = 1; m < 64; m <<= 1) v += __shfl_xor(v, m);
  __shared__ float red[2];
  if ((cc & 63) == 0) red[cc >> 6] = v;
  __syncthreads();
  if (cc == 0) outp[b] = red[0] + red[1] + ebb[0];
}

// ---------------------------------------------------------------- launch
extern "C" void kernel_launch(void* const* d_in, const int* in_sizes, int n_in,
                              void* d_out, int out_size, void* d_ws, size_t ws_size,
                              hipStream_t stream) {
  (void)in_sizes; (void)n_in; (void)out_size; (void)ws_size;
  const float* tert    = (const float*)d_in[0];
  const float* noise   = (const float*)d_in[3];
  const float* embed_w = (const float*)d_in[4];
  const float* embed_b = (const float*)d_in[5];
  const float* wq = (const float*)d_in[6];
  const float* wk = (const float*)d_in[7];
  const float* wv = (const float*)d_in[8];
  const float* wo = (const float*)d_in[9];
  const float* w1 = (const float*)d_in[10];
  const float* b1 = (const float*)d_in[11];
  const float* w2 = (const float*)d_in[12];
  const float* b2 = (const float*)d_in[13];
  const float* w3 = (const float*)d_in[14];
  const float* b3 = (const float*)d_in[15];
  const float* pw = (const float*)d_in[16];
  const float* pb = (const float*)d_in[17];
  const float* ew = (const float*)d_in[18];
  const float* eb = (const float*)d_in[19];
  float* outp = (float*)d_out;

  char* W = (char*)d_ws;
  float* pos  = (float*)W;        W += 393216;     // N*3 f32
  float* R    = (float*)W;        W += 1179648;    // N*9 f32
  int*   nbr  = (int*)W;          W += 1966080;    // N*15 i32
  _Float16* edge = (_Float16*)W;  W += 31457280;   // N*15*32 f16
  _Float16* h    = (_Float16*)W;  W += 8388608;    // N*128 f16
  _Float16* q    = (_Float16*)W;  W += 8388608;
  _Float16* hk   = (_Float16*)W;  W += 8388608;
  _Float16* hv   = (_Float16*)W;  W += 8388608;
  _Float16* o    = (_Float16*)W;  W += 8388608;
  _Float16* qkw_g = (_Float16*)W; W += 16777216;   // N*256 f16
  _Float16* pe_g  = (_Float16*)W; W += 16777216;   // N*256 f16
  _Float16* xa   = (_Float16*)W;  W += 4194304;    // B*256*128 f16
  _Float16* xb   = (_Float16*)W;  W += 2097152;    // B*128*128 f16
  _Float16* wbt  = (_Float16*)W;  W += 688128;     // 21*16384 f16
  _Float16* wqk  = (_Float16*)W;  W += 196608;     // 3*2*16384 f16
  _Float16* wpe  = (_Float16*)W;  W += 196608;     // 3*2*16384 f16
  _Float16* wct  = (_Float16*)W;  W += 393216;     // 12*16384 f16

  k_frames<<<128, 256, 0, stream>>>(tert, pos, R);
  k_knn<<<8192, 256, 0, stream>>>(pos, noise, nbr);
  k_edge<<<1920, 256, 0, stream>>>(pos, R, nbr, edge);
  k_hinit<<<512, 256, 0, stream>>>(embed_w, embed_b, h);
  k_prepw<<<1344, 256, 0, stream>>>(wq, wk, wv, wo, w1, w2, w3, wbt);
  k_prepqk<<<384, 256, 0, stream>>>(wq, wk, wqk);
  k_preppe<<<384, 256, 0, stream>>>(wv, wo, wpe);
  k_prepcw<<<768, 256, 0, stream>>>(pw, wct);

  const _Float16* wt[3][7];
  for (int l = 0; l < 3; l++)
    for (int w = 0; w < 7; w++) wt[l][w] = wbt + (size_t)(l * 7 + w) * 16384;
  const _Float16* wqk_l[3][2];
  const _Float16* wpe_l[3][2];
  for (int l = 0; l < 3; l++)
    for (int bk = 0; bk < 2; bk++) {
      wqk_l[l][bk] = wqk + (size_t)(l * 2 + bk) * 16384;
      wpe_l[l][bk] = wpe + (size_t)(l * 2 + bk) * 16384;
    }

  k_qkv<<<512, 256, 0, stream>>>(h, wt[0][0], wt[0][1], wt[0][2],
                                 wqk_l[0][0], wqk_l[0][1], q, hk, hv, qkw_g);
  for (int l = 0; l < 3; l++) {
    k_attn<<<1024, 256, 0, stream>>>(q, hk, hv, nbr, edge, qkw_g, o, pe_g);
    int nl = l + 1;
    int do_qkv = (nl < 3) ? 1 : 0;
    k_post<<<512, 256, 0, stream>>>(o, pe_g, h, wt[l][3],
                                    wpe_l[l][0], wpe_l[l][1],
                                    wt[l][4], b1 + l * 128,
                                    wt[l][5], b2 + l * 128,
                                    wt[l][6], b3 + l * 128,
                                    do_qkv ? wt[nl][0] : nullptr,
                                    do_qkv ? wt[nl][1] : nullptr,
                                    do_qkv ? wt[nl][2] : nullptr,
                                    do_qkv ? wqk_l[nl][0] : nullptr,
                                    do_qkv ? wqk_l[nl][1] : nullptr,
                                    q, hk, hv, qkw_g, do_qkv);
  }

  k_convpool_m<<<dim3(8, 64), 256, 0, stream>>>(h,  wct + 0 * 49152, pb + 0,   xa, 512);
  k_convpool_m<<<dim3(4, 64), 256, 0, stream>>>(xa, wct + 1 * 49152, pb + 128, xb, 256);
  k_convpool_m<<<dim3(2, 64), 256, 0, stream>>>(xb, wct + 2 * 49152, pb + 256, xa, 128);
  k_convpool_m<<<dim3(1, 64), 256, 0, stream>>>(xa, wct + 3 * 49152, pb + 384, xb, 64);
  k_final<<<64, 128, 0, stream>>>(xb, ew, eb, outp);
}